// Round 1
// baseline (2057.720 us; speedup 1.0000x reference)
//
#include <hip/hip_runtime.h>

typedef __attribute__((ext_vector_type(8))) __bf16 bf16x8;
typedef __attribute__((ext_vector_type(8))) unsigned short ushort8;
typedef __attribute__((ext_vector_type(4))) float floatx4;

#define NB 2
#define SEQ 2048
#define DIM 384
#define NH 8
#define HD 48
#define HDP 64
#define FF 1536
#define NLAYER 8
#define ATT_SCALE 0.14433756729740643f  // 1/sqrt(48)

__device__ __forceinline__ unsigned short f2bf(float f) {
  unsigned u = __builtin_bit_cast(unsigned, f);
  u += 0x7fffu + ((u >> 16) & 1u);
  return (unsigned short)(u >> 16);
}
__device__ __forceinline__ float bf2f(unsigned short h) {
  unsigned u = ((unsigned)h) << 16;
  return __builtin_bit_cast(float, u);
}
__device__ __forceinline__ bf16x8 ldb8(const unsigned short* p) {
  return __builtin_bit_cast(bf16x8, *(const ushort8*)p);
}
#define MFMA(a, b, c) __builtin_amdgcn_mfma_f32_16x16x32_bf16(a, b, c, 0, 0, 0)

// ---------------- weight transpose+convert: W (K x N) fp32 -> Wt (N x K) bf16, per layer z ----
__global__ __launch_bounds__(256) void wtrans_kernel(const float* __restrict__ W,
                                                     unsigned short* __restrict__ Wt,
                                                     int K, int N) {
  __shared__ unsigned short tile[32][33];
  size_t lstride = (size_t)K * N;
  const float* Wl = W + (size_t)blockIdx.z * lstride;
  unsigned short* Wtl = Wt + (size_t)blockIdx.z * lstride;
  int n0 = blockIdx.x * 32, k0 = blockIdx.y * 32;
  int tx = threadIdx.x, ty = threadIdx.y;  // block (32,8)
  for (int i = ty; i < 32; i += 8)
    tile[i][tx] = f2bf(Wl[(size_t)(k0 + i) * N + n0 + tx]);
  __syncthreads();
  for (int i = ty; i < 32; i += 8)
    Wtl[(size_t)(n0 + i) * K + k0 + tx] = tile[tx][i];
}

// ---------------- rope tables ----------------
__global__ void ropetab_kernel(float* __restrict__ cosT, float* __restrict__ sinT) {
  int idx = blockIdx.x * 256 + threadIdx.x;
  if (idx >= SEQ * HD) return;
  int l = idx / HD, d = idx % HD;
  int j = d % 24;
  float inv = powf(10000.0f, -(float)j / 24.0f);
  float pos;
  if (j < 6) pos = (float)(l >> 8);
  else if (j < 15) pos = (float)((l >> 4) & 15);
  else pos = (float)(l & 15);
  float f = pos * inv;
  cosT[idx] = cosf(f);
  sinT[idx] = sinf(f);
}

// ---------------- gather (ids_restore) + input RMS -> fp32 stream x ----------------
__global__ __launch_bounds__(256) void gatherrms_kernel(const float* __restrict__ vis,
                                                        const int* __restrict__ ids,
                                                        const float* __restrict__ mask_token,
                                                        const float* __restrict__ w,
                                                        float* __restrict__ x) {
  int wv = threadIdx.x >> 6, lane = threadIdx.x & 63;
  int row = blockIdx.x * 4 + wv;  // b*2048 + l
  int b = row >> 11;
  int src = ids[row];
  const float* p = (src < 512) ? (vis + ((size_t)b * 512 + src) * DIM) : mask_token;
  float v[6];
  float ss = 0.f;
#pragma unroll
  for (int j = 0; j < 6; j++) { v[j] = p[lane + 64 * j]; ss += v[j] * v[j]; }
#pragma unroll
  for (int m = 32; m; m >>= 1) ss += __shfl_xor(ss, m);
  float s = rsqrtf(ss * (1.0f / DIM) + 1e-6f);
#pragma unroll
  for (int j = 0; j < 6; j++)
    x[(size_t)row * DIM + lane + 64 * j] = v[j] * s * w[lane + 64 * j];
}

// ---------------- RMS (fp32 in) -> bf16 out ----------------
__global__ __launch_bounds__(256) void rmsbf_kernel(const float* __restrict__ x,
                                                    const float* __restrict__ w,
                                                    unsigned short* __restrict__ out) {
  int wv = threadIdx.x >> 6, lane = threadIdx.x & 63;
  int row = blockIdx.x * 4 + wv;
  const float* xr = x + (size_t)row * DIM;
  float v[6];
  float ss = 0.f;
#pragma unroll
  for (int j = 0; j < 6; j++) { v[j] = xr[lane + 64 * j]; ss += v[j] * v[j]; }
#pragma unroll
  for (int m = 32; m; m >>= 1) ss += __shfl_xor(ss, m);
  float s = rsqrtf(ss * (1.0f / DIM) + 1e-6f);
#pragma unroll
  for (int j = 0; j < 6; j++)
    out[(size_t)row * DIM + lane + 64 * j] = f2bf(v[j] * s * w[lane + 64 * j]);
}

// ---------------- generic bf16 MFMA GEMM: C = A(MxK) * Wt(NxK)^T + bias ----------------
// mode 0: outb bf16 row-major      mode 1: v -> vt[b][h][hd][l] (transposed scatter)
// mode 2: outf (fp32) += acc+bias  mode 3: gelu -> outb bf16
__global__ __launch_bounds__(256) void gemm_kernel(const unsigned short* __restrict__ A,
                                                   const unsigned short* __restrict__ Wt,
                                                   const float* __restrict__ bias,
                                                   int M, int N, int K, int mode,
                                                   unsigned short* __restrict__ outb,
                                                   float* __restrict__ outf) {
  __shared__ __align__(16) unsigned short As[64][40];
  __shared__ __align__(16) unsigned short Bs[64][40];
  int tid = threadIdx.x;
  int wv = tid >> 6, lane = tid & 63;
  int wm = wv >> 1, wn = wv & 1;
  int row0 = blockIdx.x * 64, col0 = blockIdx.y * 64;
  int q = lane >> 4, c = lane & 15;
  floatx4 acc[2][2] = {};
  int srow = tid >> 2, sk = (tid & 3) * 8;
  const unsigned short* Ap = A + (size_t)(row0 + srow) * K + sk;
  const unsigned short* Bp = Wt + (size_t)(col0 + srow) * K + sk;
  for (int k0 = 0; k0 < K; k0 += 32) {
    *(ushort8*)(&As[srow][sk]) = *(const ushort8*)(Ap + k0);
    *(ushort8*)(&Bs[srow][sk]) = *(const ushort8*)(Bp + k0);
    __syncthreads();
    bf16x8 a0 = ldb8(&As[wm * 32 + c][q * 8]);
    bf16x8 a1 = ldb8(&As[wm * 32 + 16 + c][q * 8]);
    bf16x8 b0 = ldb8(&Bs[wn * 32 + c][q * 8]);
    bf16x8 b1 = ldb8(&Bs[wn * 32 + 16 + c][q * 8]);
    acc[0][0] = MFMA(a0, b0, acc[0][0]);
    acc[0][1] = MFMA(a0, b1, acc[0][1]);
    acc[1][0] = MFMA(a1, b0, acc[1][0]);
    acc[1][1] = MFMA(a1, b1, acc[1][1]);
    __syncthreads();
  }
#pragma unroll
  for (int tm = 0; tm < 2; tm++)
#pragma unroll
    for (int tn = 0; tn < 2; tn++)
#pragma unroll
      for (int r = 0; r < 4; r++) {
        int rg = row0 + wm * 32 + tm * 16 + q * 4 + r;
        int cg = col0 + wn * 32 + tn * 16 + c;
        float v = acc[tm][tn][r] + bias[cg];
        if (mode == 0) {
          outb[(size_t)rg * N + cg] = f2bf(v);
        } else if (mode == 1) {
          int h = cg / HD, hd = cg % HD;
          int b = rg >> 11, l = rg & 2047;
          outb[(((size_t)b * NH + h) * HDP + hd) * SEQ + l] = f2bf(v);
        } else if (mode == 2) {
          outf[(size_t)rg * N + cg] += v;
        } else {
          float g = v * 0.5f * (1.0f + erff(v * 0.70710678f));
          outb[(size_t)rg * N + cg] = f2bf(g);
        }
      }
}

// ---------------- rope: qpre/kpre (bf16 row-major, bias applied) -> q/k [b][h][l][64] ----------
__global__ __launch_bounds__(384) void rope_kernel(const unsigned short* __restrict__ qpre,
                                                   const unsigned short* __restrict__ kpre,
                                                   const float* __restrict__ cosT,
                                                   const float* __restrict__ sinT,
                                                   unsigned short* __restrict__ qdst,
                                                   unsigned short* __restrict__ kdst) {
  int row = blockIdx.x;  // b*2048 + l
  int b = row >> 11, l = row & 2047;
  int t = threadIdx.x;
  const unsigned short* src = (t >= 192) ? kpre : qpre;
  unsigned short* dst = (t >= 192) ? kdst : qdst;
  int pp = t % 192;
  int h = pp / 24, d = pp % 24;
  float x1 = bf2f(src[(size_t)row * DIM + h * HD + d]);
  float x2 = bf2f(src[(size_t)row * DIM + h * HD + d + 24]);
  float cs = cosT[l * HD + d], sn = sinT[l * HD + d];  // freq identical at d and d+24
  size_t base = (((size_t)b * NH + h) * SEQ + l) * HDP;
  dst[base + d] = f2bf(x1 * cs - x2 * sn);
  dst[base + d + 24] = f2bf(x2 * cs + x1 * sn);
}

// ---------------- attention: one block per (b,h, 16 q-rows) ----------------
// P LDS layout tiled: addr(row,k) = (k>>4)*256 + row*16 + (k&15)   (exactly 64 KB)
__global__ __launch_bounds__(256) void attn_kernel(const unsigned short* __restrict__ qb,
                                                   const unsigned short* __restrict__ kb,
                                                   const unsigned short* __restrict__ vt,
                                                   unsigned short* __restrict__ obuf,
                                                   float* __restrict__ sums) {
  __shared__ __align__(16) unsigned short P[32768];
  int tid = threadIdx.x;
  int wv = tid >> 6, lane = tid & 63;
  int q = lane >> 4, c = lane & 15;
  int bh = blockIdx.y;  // b*8 + h
  int q0 = blockIdx.x * 16;
  int kstart = q0 & ~255;  // frame-aligned: only k >= kstart allowed
  const unsigned short* qbase = qb + (size_t)bh * SEQ * HDP;
  const unsigned short* kbase = kb + (size_t)bh * SEQ * HDP;
  // Q fragments (all waves identical): A[m=c][kk]
  bf16x8 a0 = ldb8(qbase + (size_t)(q0 + c) * HDP + q * 8);
  bf16x8 a1 = ldb8(qbase + (size_t)(q0 + c) * HDP + 32 + q * 8);
  // scores -> P (bf16, scaled)
  int t0 = kstart >> 4;
  for (int t = t0 + wv; t < 128; t += 4) {
    const unsigned short* krow = kbase + (size_t)(t * 16 + c) * HDP;
    bf16x8 b0 = ldb8(krow + q * 8);
    bf16x8 b1 = ldb8(krow + 32 + q * 8);
    floatx4 s = {};
    s = MFMA(a0, b0, s);
    s = MFMA(a1, b1, s);
#pragma unroll
    for (int r = 0; r < 4; r++)
      P[t * 256 + (q * 4 + r) * 16 + c] = f2bf(s[r] * ATT_SCALE);
  }
  __syncthreads();
  // softmax: wave wv owns rows wv*4 + q; 16 lanes (c) stride the row
  int row = wv * 4 + q;
  float m = -3.0e38f;
  for (int kk = kstart + c; kk < SEQ; kk += 16)
    m = fmaxf(m, bf2f(P[(kk >> 4) * 256 + row * 16 + c]));
#pragma unroll
  for (int msk = 1; msk < 16; msk <<= 1) m = fmaxf(m, __shfl_xor(m, msk));
  float sum = 0.f;
  for (int kk = kstart + c; kk < SEQ; kk += 16) {
    int ad = (kk >> 4) * 256 + row * 16 + c;
    float e = __expf(bf2f(P[ad]) - m);
    sum += e;
    P[ad] = f2bf(e);
  }
#pragma unroll
  for (int msk = 1; msk < 16; msk <<= 1) sum += __shfl_xor(sum, msk);
  float* bsums = sums + ((size_t)blockIdx.y * gridDim.x + blockIdx.x) * 16;
  if (c == 0) bsums[row] = 1.0f / sum;
  __syncthreads();
  // PV: wave wv -> output cols wv*16 .. (only wv<3 are real, 48..63 is pad)
  floatx4 acc = {};
  const unsigned short* vrow = vt + ((size_t)bh * HDP + wv * 16 + c) * SEQ;
  for (int kk = kstart; kk < SEQ; kk += 32) {
    bf16x8 a = ldb8(&P[((kk + q * 8) >> 4) * 256 + c * 16 + ((q & 1) * 8)]);
    bf16x8 bfr = ldb8(vrow + kk + q * 8);
    acc = MFMA(a, bfr, acc);
  }
  if (wv < 3) {
    int b = bh >> 3, h = bh & 7;
#pragma unroll
    for (int r = 0; r < 4; r++) {
      int qr = q * 4 + r;
      float o = acc[r] * bsums[qr];
      obuf[((size_t)b * SEQ + q0 + qr) * DIM + h * HD + wv * 16 + c] = f2bf(o);
    }
  }
}

// ---------------- stable argsort(-mask) ranks -> dest row in [0,2048) ----------------
__global__ void rank_kernel(const int* __restrict__ mask, int* __restrict__ dest) {
  int idx = blockIdx.x * 256 + threadIdx.x;
  if (idx >= NB * SEQ) return;
  int b = idx >> 11, l = idx & 2047;
  const int* mb = mask + b * SEQ;
  int p1 = 0;
  for (int j = 0; j < l; j++) p1 += mb[j];
  dest[idx] = mb[l] ? p1 : 512 + (l - p1);
}

// ---------------- write decoded_full + scattered visible/masked ----------------
__global__ __launch_bounds__(256) void output_kernel(const float* __restrict__ x,
                                                     const int* __restrict__ dest,
                                                     float* __restrict__ out) {
  int idx = blockIdx.x * 256 + threadIdx.x;  // NB*SEQ*96
  int row = idx / 96, c = idx % 96;
  float4 v = ((const float4*)(x + (size_t)row * DIM))[c];
  ((float4*)(out + (size_t)row * DIM))[c] = v;
  int b = row >> 11;
  int d = dest[row];
  size_t base = (size_t)NB * SEQ * DIM;
  size_t o;
  if (d < 512) o = base + ((size_t)b * 512 + d) * DIM;
  else o = base + (size_t)NB * 512 * DIM + ((size_t)b * 1536 + (d - 512)) * DIM;
  ((float4*)(out + o))[c] = v;
}

extern "C" void kernel_launch(void* const* d_in, const int* in_sizes, int n_in,
                              void* d_out, int out_size, void* d_ws, size_t ws_size,
                              hipStream_t stream) {
  const float* vis = (const float*)d_in[0];
  const int* ids = (const int*)d_in[1];
  const int* mask = (const int*)d_in[2];
  const float* mask_token = (const float*)d_in[6];
  const float* ln_in_w = (const float*)d_in[7];
  const float* ln1_w = (const float*)d_in[8];
  const float* ln2_w = (const float*)d_in[9];
  const float* Wq = (const float*)d_in[10];
  const float* bq = (const float*)d_in[11];
  const float* Wk = (const float*)d_in[12];
  const float* bk = (const float*)d_in[13];
  const float* Wv = (const float*)d_in[14];
  const float* bv = (const float*)d_in[15];
  const float* Wo = (const float*)d_in[16];
  const float* bo = (const float*)d_in[17];
  const float* W1 = (const float*)d_in[18];
  const float* b1 = (const float*)d_in[19];
  const float* W2 = (const float*)d_in[20];
  const float* b2 = (const float*)d_in[21];

  char* p = (char*)d_ws;
  size_t off = 0;
  auto alloc = [&](size_t n) -> void* {
    off = (off + 255) & ~(size_t)255;
    void* r = p + off;
    off += n;
    return r;
  };
  unsigned short* wqT = (unsigned short*)alloc((size_t)NLAYER * DIM * DIM * 2);
  unsigned short* wkT = (unsigned short*)alloc((size_t)NLAYER * DIM * DIM * 2);
  unsigned short* wvT = (unsigned short*)alloc((size_t)NLAYER * DIM * DIM * 2);
  unsigned short* woT = (unsigned short*)alloc((size_t)NLAYER * DIM * DIM * 2);
  unsigned short* w1T = (unsigned short*)alloc((size_t)NLAYER * DIM * FF * 2);
  unsigned short* w2T = (unsigned short*)alloc((size_t)NLAYER * DIM * FF * 2);
  float* cosT = (float*)alloc((size_t)SEQ * HD * 4);
  float* sinT = (float*)alloc((size_t)SEQ * HD * 4);
  float* x = (float*)alloc((size_t)NB * SEQ * DIM * 4);
  unsigned short* hdn = (unsigned short*)alloc((size_t)NB * SEQ * DIM * 2);
  unsigned short* qpre = (unsigned short*)alloc((size_t)NB * SEQ * DIM * 2);
  unsigned short* kpre = (unsigned short*)alloc((size_t)NB * SEQ * DIM * 2);
  unsigned short* qb = (unsigned short*)alloc((size_t)NB * NH * SEQ * HDP * 2);
  unsigned short* kb = (unsigned short*)alloc((size_t)NB * NH * SEQ * HDP * 2);
  unsigned short* vtb = (unsigned short*)alloc((size_t)NB * NH * SEQ * HDP * 2);
  unsigned short* obuf = (unsigned short*)alloc((size_t)NB * SEQ * DIM * 2);
  unsigned short* a1 = (unsigned short*)alloc((size_t)NB * SEQ * FF * 2);
  float* sums = (float*)alloc((size_t)16 * 128 * 16 * 4);
  int* dest = (int*)alloc((size_t)NB * SEQ * 4);

  // zero head-dim pad [48,64) once per call (ws is re-poisoned before every launch)
  hipMemsetAsync(qb, 0, (size_t)NB * NH * SEQ * HDP * 2, stream);
  hipMemsetAsync(kb, 0, (size_t)NB * NH * SEQ * HDP * 2, stream);
  hipMemsetAsync(vtb, 0, (size_t)NB * NH * SEQ * HDP * 2, stream);

  dim3 tb(32, 8);
  wtrans_kernel<<<dim3(12, 12, 8), tb, 0, stream>>>(Wq, wqT, DIM, DIM);
  wtrans_kernel<<<dim3(12, 12, 8), tb, 0, stream>>>(Wk, wkT, DIM, DIM);
  wtrans_kernel<<<dim3(12, 12, 8), tb, 0, stream>>>(Wv, wvT, DIM, DIM);
  wtrans_kernel<<<dim3(12, 12, 8), tb, 0, stream>>>(Wo, woT, DIM, DIM);
  wtrans_kernel<<<dim3(48, 12, 8), tb, 0, stream>>>(W1, w1T, DIM, FF);
  wtrans_kernel<<<dim3(12, 48, 8), tb, 0, stream>>>(W2, w2T, FF, DIM);
  ropetab_kernel<<<(SEQ * HD + 255) / 256, 256, 0, stream>>>(cosT, sinT);
  gatherrms_kernel<<<NB * SEQ / 4, 256, 0, stream>>>(vis, ids, mask_token, ln_in_w, x);

  for (int i = 0; i < NLAYER; i++) {
    size_t wo = (size_t)i * DIM * DIM;
    size_t wf = (size_t)i * DIM * FF;
    rmsbf_kernel<<<NB * SEQ / 4, 256, 0, stream>>>(x, ln1_w + i * DIM, hdn);
    gemm_kernel<<<dim3(64, 6), 256, 0, stream>>>(hdn, wqT + wo, bq + i * DIM, NB * SEQ, DIM, DIM, 0, qpre, nullptr);
    gemm_kernel<<<dim3(64, 6), 256, 0, stream>>>(hdn, wkT + wo, bk + i * DIM, NB * SEQ, DIM, DIM, 0, kpre, nullptr);
    gemm_kernel<<<dim3(64, 6), 256, 0, stream>>>(hdn, wvT + wo, bv + i * DIM, NB * SEQ, DIM, DIM, 1, vtb, nullptr);
    rope_kernel<<<NB * SEQ, 384, 0, stream>>>(qpre, kpre, cosT, sinT, qb, kb);
    attn_kernel<<<dim3(128, 16), 256, 0, stream>>>(qb, kb, vtb, obuf, sums);
    gemm_kernel<<<dim3(64, 6), 256, 0, stream>>>(obuf, woT + wo, bo + i * DIM, NB * SEQ, DIM, DIM, 2, nullptr, x);
    rmsbf_kernel<<<NB * SEQ / 4, 256, 0, stream>>>(x, ln2_w + i * DIM, hdn);
    gemm_kernel<<<dim3(64, 24), 256, 0, stream>>>(hdn, w1T + wf, b1 + i * FF, NB * SEQ, FF, DIM, 3, a1, nullptr);
    gemm_kernel<<<dim3(64, 6), 256, 0, stream>>>(a1, w2T + wf, b2 + i * DIM, NB * SEQ, DIM, FF, 2, nullptr, x);
  }
  rank_kernel<<<(NB * SEQ + 255) / 256, 256, 0, stream>>>(mask, dest);
  output_kernel<<<NB * SEQ * 96 / 256, 256, 0, stream>>>(x, dest, (float*)d_out);
}

// Round 2
// 1735.205 us; speedup vs baseline: 1.1859x; 1.1859x over previous
//
#include <hip/hip_runtime.h>

typedef __attribute__((ext_vector_type(8))) __bf16 bf16x8;
typedef __attribute__((ext_vector_type(8))) unsigned short ushort8;
typedef __attribute__((ext_vector_type(4))) float floatx4;

#define NB 2
#define SEQ 2048
#define DIM 384
#define NH 8
#define HD 48
#define HDP 64
#define FF 1536
#define NLAYER 8
#define ATT_SCALE 0.14433756729740643f  // 1/sqrt(48)

__device__ __forceinline__ unsigned short f2bf(float f) {
  unsigned u = __builtin_bit_cast(unsigned, f);
  u += 0x7fffu + ((u >> 16) & 1u);
  return (unsigned short)(u >> 16);
}
__device__ __forceinline__ float bf2f(unsigned short h) {
  unsigned u = ((unsigned)h) << 16;
  return __builtin_bit_cast(float, u);
}
__device__ __forceinline__ bf16x8 ldb8(const unsigned short* p) {
  return __builtin_bit_cast(bf16x8, *(const ushort8*)p);
}
#define MFMA(a, b, c) __builtin_amdgcn_mfma_f32_16x16x32_bf16(a, b, c, 0, 0, 0)

// ---------------- weight transpose+convert: W (K x N) fp32 -> Wt (N x K) bf16 ----
__global__ __launch_bounds__(256) void wtrans_kernel(const float* __restrict__ W,
                                                     unsigned short* __restrict__ Wt,
                                                     int K, int N,
                                                     size_t sstride, size_t dstride) {
  __shared__ unsigned short tile[32][33];
  const float* Wl = W + (size_t)blockIdx.z * sstride;
  unsigned short* Wtl = Wt + (size_t)blockIdx.z * dstride;
  int n0 = blockIdx.x * 32, k0 = blockIdx.y * 32;
  int tx = threadIdx.x, ty = threadIdx.y;  // block (32,8)
  for (int i = ty; i < 32; i += 8)
    tile[i][tx] = f2bf(Wl[(size_t)(k0 + i) * N + n0 + tx]);
  __syncthreads();
  for (int i = ty; i < 32; i += 8)
    Wtl[(size_t)(n0 + i) * K + k0 + tx] = tile[tx][i];
}

// ---------------- qkv bias concat [8][1152] ----------------
__global__ void biascat_kernel(const float* __restrict__ bq, const float* __restrict__ bk,
                               const float* __restrict__ bv, float* __restrict__ out) {
  int idx = blockIdx.x * 256 + threadIdx.x;
  if (idx >= NLAYER * 1152) return;
  int z = idx / 1152, j = idx % 1152;
  float v = (j < 384) ? bq[z * 384 + j] : (j < 768) ? bk[z * 384 + j - 384] : bv[z * 384 + j - 768];
  out[idx] = v;
}

// ---------------- rope tables ----------------
__global__ void ropetab_kernel(float* __restrict__ cosT, float* __restrict__ sinT) {
  int idx = blockIdx.x * 256 + threadIdx.x;
  if (idx >= SEQ * HD) return;
  int l = idx / HD, d = idx % HD;
  int j = d % 24;
  float inv = powf(10000.0f, -(float)j / 24.0f);
  float pos;
  if (j < 6) pos = (float)(l >> 8);
  else if (j < 15) pos = (float)((l >> 4) & 15);
  else pos = (float)(l & 15);
  float f = pos * inv;
  cosT[idx] = cosf(f);
  sinT[idx] = sinf(f);
}

// ---------------- gather (ids_restore) + input RMS -> fp32 stream x ----------------
__global__ __launch_bounds__(256) void gatherrms_kernel(const float* __restrict__ vis,
                                                        const int* __restrict__ ids,
                                                        const float* __restrict__ mask_token,
                                                        const float* __restrict__ w,
                                                        float* __restrict__ x) {
  int wv = threadIdx.x >> 6, lane = threadIdx.x & 63;
  int row = blockIdx.x * 4 + wv;  // b*2048 + l
  int b = row >> 11;
  int src = ids[row];
  const float* p = (src < 512) ? (vis + ((size_t)b * 512 + src) * DIM) : mask_token;
  float v[6];
  float ss = 0.f;
#pragma unroll
  for (int j = 0; j < 6; j++) { v[j] = p[lane + 64 * j]; ss += v[j] * v[j]; }
#pragma unroll
  for (int m = 32; m; m >>= 1) ss += __shfl_xor(ss, m);
  float s = rsqrtf(ss * (1.0f / DIM) + 1e-6f);
#pragma unroll
  for (int j = 0; j < 6; j++)
    x[(size_t)row * DIM + lane + 64 * j] = v[j] * s * w[lane + 64 * j];
}

// ---------------- RMS (fp32 in) -> bf16 out ----------------
__global__ __launch_bounds__(256) void rmsbf_kernel(const float* __restrict__ x,
                                                    const float* __restrict__ w,
                                                    unsigned short* __restrict__ out) {
  int wv = threadIdx.x >> 6, lane = threadIdx.x & 63;
  int row = blockIdx.x * 4 + wv;
  const float* xr = x + (size_t)row * DIM;
  float v[6];
  float ss = 0.f;
#pragma unroll
  for (int j = 0; j < 6; j++) { v[j] = xr[lane + 64 * j]; ss += v[j] * v[j]; }
#pragma unroll
  for (int m = 32; m; m >>= 1) ss += __shfl_xor(ss, m);
  float s = rsqrtf(ss * (1.0f / DIM) + 1e-6f);
#pragma unroll
  for (int j = 0; j < 6; j++)
    out[(size_t)row * DIM + lane + 64 * j] = f2bf(v[j] * s * w[lane + 64 * j]);
}

// ---------------- generic bf16 MFMA GEMM: C = A(MxK) * Wt(NxK)^T + bias ----------------
// mode 2: outf (fp32) += acc+bias   mode 3: gelu -> outb bf16
// mode 4: qkv split: n<384 -> outb (q row-major), <768 -> outb2 (k row-major),
//         else v -> outv[b][h][hd][l] transposed scatter
__global__ __launch_bounds__(256) void gemm_kernel(const unsigned short* __restrict__ A,
                                                   const unsigned short* __restrict__ Wt,
                                                   const float* __restrict__ bias,
                                                   int M, int N, int K, int mode,
                                                   unsigned short* __restrict__ outb,
                                                   unsigned short* __restrict__ outb2,
                                                   unsigned short* __restrict__ outv,
                                                   float* __restrict__ outf) {
  __shared__ __align__(16) unsigned short As[64][40];
  __shared__ __align__(16) unsigned short Bs[64][40];
  int tid = threadIdx.x;
  int wv = tid >> 6, lane = tid & 63;
  int wm = wv >> 1, wn = wv & 1;
  int row0 = blockIdx.x * 64, col0 = blockIdx.y * 64;
  int q = lane >> 4, c = lane & 15;
  floatx4 acc[2][2] = {};
  int srow = tid >> 2, sk = (tid & 3) * 8;
  const unsigned short* Ap = A + (size_t)(row0 + srow) * K + sk;
  const unsigned short* Bp = Wt + (size_t)(col0 + srow) * K + sk;
  for (int k0 = 0; k0 < K; k0 += 32) {
    *(ushort8*)(&As[srow][sk]) = *(const ushort8*)(Ap + k0);
    *(ushort8*)(&Bs[srow][sk]) = *(const ushort8*)(Bp + k0);
    __syncthreads();
    bf16x8 a0 = ldb8(&As[wm * 32 + c][q * 8]);
    bf16x8 a1 = ldb8(&As[wm * 32 + 16 + c][q * 8]);
    bf16x8 b0 = ldb8(&Bs[wn * 32 + c][q * 8]);
    bf16x8 b1 = ldb8(&Bs[wn * 32 + 16 + c][q * 8]);
    acc[0][0] = MFMA(a0, b0, acc[0][0]);
    acc[0][1] = MFMA(a0, b1, acc[0][1]);
    acc[1][0] = MFMA(a1, b0, acc[1][0]);
    acc[1][1] = MFMA(a1, b1, acc[1][1]);
    __syncthreads();
  }
#pragma unroll
  for (int tm = 0; tm < 2; tm++)
#pragma unroll
    for (int tn = 0; tn < 2; tn++)
#pragma unroll
      for (int r = 0; r < 4; r++) {
        int rg = row0 + wm * 32 + tm * 16 + q * 4 + r;
        int cg = col0 + wn * 32 + tn * 16 + c;
        float v = acc[tm][tn][r] + bias[cg];
        if (mode == 2) {
          outf[(size_t)rg * N + cg] += v;
        } else if (mode == 3) {
          float g = v * 0.5f * (1.0f + erff(v * 0.70710678f));
          outb[(size_t)rg * N + cg] = f2bf(g);
        } else {  // mode 4
          if (cg < 384) {
            outb[(size_t)rg * 384 + cg] = f2bf(v);
          } else if (cg < 768) {
            outb2[(size_t)rg * 384 + cg - 384] = f2bf(v);
          } else {
            int j = cg - 768;
            int h = j / HD, hd = j % HD;
            int b = rg >> 11, l = rg & 2047;
            outv[(((size_t)b * NH + h) * HDP + hd) * SEQ + l] = f2bf(v);
          }
        }
      }
}

// ---------------- rope: qpre/kpre (bf16 row-major) -> q/k [b][h][l][64]; q scaled ----------
__global__ __launch_bounds__(384) void rope_kernel(const unsigned short* __restrict__ qpre,
                                                   const unsigned short* __restrict__ kpre,
                                                   const float* __restrict__ cosT,
                                                   const float* __restrict__ sinT,
                                                   unsigned short* __restrict__ qdst,
                                                   unsigned short* __restrict__ kdst) {
  int row = blockIdx.x;  // b*2048 + l
  int b = row >> 11, l = row & 2047;
  int t = threadIdx.x;
  const unsigned short* src = (t >= 192) ? kpre : qpre;
  unsigned short* dst = (t >= 192) ? kdst : qdst;
  float sc = (t >= 192) ? 1.0f : ATT_SCALE;  // fold 1/sqrt(hd) into q
  int pp = t % 192;
  int h = pp / 24, d = pp % 24;
  float x1 = bf2f(src[(size_t)row * DIM + h * HD + d]);
  float x2 = bf2f(src[(size_t)row * DIM + h * HD + d + 24]);
  float cs = cosT[l * HD + d], sn = sinT[l * HD + d];  // freq identical at d and d+24
  size_t base = (((size_t)b * NH + h) * SEQ + l) * HDP;
  dst[base + d] = f2bf((x1 * cs - x2 * sn) * sc);
  dst[base + d + 24] = f2bf((x2 * cs + x1 * sn) * sc);
}

// ---------------- flash attention: 1 wave = 16 q-rows, online softmax in regs -------------
// Q pre-scaled by ATT_SCALE. frame mask: k >= (q0 & ~255).
__global__ __launch_bounds__(64) void fattn_kernel(const unsigned short* __restrict__ qb,
                                                   const unsigned short* __restrict__ kb,
                                                   const unsigned short* __restrict__ vt,
                                                   unsigned short* __restrict__ obuf) {
  __shared__ __align__(16) unsigned short Pt[16][72];  // A-layout P scratch (16B-aligned rows)
  int lane = threadIdx.x;
  int q = lane >> 4, c = lane & 15;
  int bh = blockIdx.y;
  int q0 = blockIdx.x * 16;
  int kstart = q0 & ~255;
  const unsigned short* qbase = qb + (size_t)bh * SEQ * HDP;
  const unsigned short* kbase = kb + (size_t)bh * SEQ * HDP;
  const unsigned short* vbase = vt + (size_t)bh * HDP * SEQ;
  // Q A-frags: A[m=c][k=q*8+j], head-dim split 0..31 / 32..63 (pad 48..63 zeroed)
  bf16x8 a0 = ldb8(qbase + (size_t)(q0 + c) * HDP + q * 8);
  bf16x8 a1 = ldb8(qbase + (size_t)(q0 + c) * HDP + 32 + q * 8);
  floatx4 O[3] = {};  // 48 head-dim cols (skip pad)
  float mr[4] = {-3e38f, -3e38f, -3e38f, -3e38f};
  float lr[4] = {0.f, 0.f, 0.f, 0.f};
  for (int k0 = kstart; k0 < SEQ; k0 += 64) {
    floatx4 S[4];
#pragma unroll
    for (int t = 0; t < 4; t++) {
      const unsigned short* krow = kbase + (size_t)(k0 + t * 16 + c) * HDP;
      bf16x8 b0 = ldb8(krow + q * 8);
      bf16x8 b1 = ldb8(krow + 32 + q * 8);
      floatx4 z = {};
      z = MFMA(a0, b0, z);
      S[t] = MFMA(a1, b1, z);
    }
    float alpha[4];
#pragma unroll
    for (int r = 0; r < 4; r++) {
      float m0 = fmaxf(fmaxf(S[0][r], S[1][r]), fmaxf(S[2][r], S[3][r]));
#pragma unroll
      for (int msk = 1; msk < 16; msk <<= 1) m0 = fmaxf(m0, __shfl_xor(m0, msk, 16));
      float nm = fmaxf(mr[r], m0);
      alpha[r] = __expf(mr[r] - nm);
      mr[r] = nm;
      lr[r] *= alpha[r];
    }
#pragma unroll
    for (int t = 0; t < 4; t++)
#pragma unroll
      for (int r = 0; r < 4; r++) {
        float pv = __expf(S[t][r] - mr[r]);
        lr[r] += pv;  // per-lane partial over c; reduced at end
        Pt[q * 4 + r][t * 16 + c] = f2bf(pv);
      }
#pragma unroll
    for (int f = 0; f < 3; f++)
#pragma unroll
      for (int r = 0; r < 4; r++) O[f][r] *= alpha[r];
    // P A-frags: A[m=c][k=q*8+j]
    bf16x8 pa0 = ldb8(&Pt[c][q * 8]);
    bf16x8 pa1 = ldb8(&Pt[c][32 + q * 8]);
#pragma unroll
    for (int f = 0; f < 3; f++) {
      const unsigned short* vrow = vbase + (size_t)(f * 16 + c) * SEQ + k0;
      bf16x8 v0 = ldb8(vrow + q * 8);
      bf16x8 v1 = ldb8(vrow + 32 + q * 8);
      O[f] = MFMA(pa0, v0, O[f]);
      O[f] = MFMA(pa1, v1, O[f]);
    }
  }
#pragma unroll
  for (int r = 0; r < 4; r++) {
#pragma unroll
    for (int msk = 1; msk < 16; msk <<= 1) lr[r] += __shfl_xor(lr[r], msk, 16);
    lr[r] = 1.0f / lr[r];
  }
  int b = bh >> 3, h = bh & 7;
#pragma unroll
  for (int f = 0; f < 3; f++)
#pragma unroll
    for (int r = 0; r < 4; r++)
      obuf[((size_t)b * SEQ + q0 + q * 4 + r) * DIM + h * HD + f * 16 + c] = f2bf(O[f][r] * lr[r]);
}

// ---------------- stable argsort(-mask) ranks -> dest row in [0,2048) ----------------
__global__ void rank_kernel(const int* __restrict__ mask, int* __restrict__ dest) {
  int idx = blockIdx.x * 256 + threadIdx.x;
  if (idx >= NB * SEQ) return;
  int b = idx >> 11, l = idx & 2047;
  const int* mb = mask + b * SEQ;
  int p1 = 0;
  for (int j = 0; j < l; j++) p1 += mb[j];
  dest[idx] = mb[l] ? p1 : 512 + (l - p1);
}

// ---------------- write decoded_full + scattered visible/masked ----------------
__global__ __launch_bounds__(256) void output_kernel(const float* __restrict__ x,
                                                     const int* __restrict__ dest,
                                                     float* __restrict__ out) {
  int idx = blockIdx.x * 256 + threadIdx.x;  // NB*SEQ*96
  int row = idx / 96, c = idx % 96;
  float4 v = ((const float4*)(x + (size_t)row * DIM))[c];
  ((float4*)(out + (size_t)row * DIM))[c] = v;
  int b = row >> 11;
  int d = dest[row];
  size_t base = (size_t)NB * SEQ * DIM;
  size_t o;
  if (d < 512) o = base + ((size_t)b * 512 + d) * DIM;
  else o = base + (size_t)NB * 512 * DIM + ((size_t)b * 1536 + (d - 512)) * DIM;
  ((float4*)(out + o))[c] = v;
}

extern "C" void kernel_launch(void* const* d_in, const int* in_sizes, int n_in,
                              void* d_out, int out_size, void* d_ws, size_t ws_size,
                              hipStream_t stream) {
  const float* vis = (const float*)d_in[0];
  const int* ids = (const int*)d_in[1];
  const int* mask = (const int*)d_in[2];
  const float* mask_token = (const float*)d_in[6];
  const float* ln_in_w = (const float*)d_in[7];
  const float* ln1_w = (const float*)d_in[8];
  const float* ln2_w = (const float*)d_in[9];
  const float* Wq = (const float*)d_in[10];
  const float* bq = (const float*)d_in[11];
  const float* Wk = (const float*)d_in[12];
  const float* bk = (const float*)d_in[13];
  const float* Wv = (const float*)d_in[14];
  const float* bv = (const float*)d_in[15];
  const float* Wo = (const float*)d_in[16];
  const float* bo = (const float*)d_in[17];
  const float* W1 = (const float*)d_in[18];
  const float* b1 = (const float*)d_in[19];
  const float* W2 = (const float*)d_in[20];
  const float* b2 = (const float*)d_in[21];

  char* p = (char*)d_ws;
  size_t off = 0;
  auto alloc = [&](size_t n) -> void* {
    off = (off + 255) & ~(size_t)255;
    void* r = p + off;
    off += n;
    return r;
  };
  unsigned short* wqkvT = (unsigned short*)alloc((size_t)NLAYER * 1152 * DIM * 2);
  unsigned short* woT = (unsigned short*)alloc((size_t)NLAYER * DIM * DIM * 2);
  unsigned short* w1T = (unsigned short*)alloc((size_t)NLAYER * DIM * FF * 2);
  unsigned short* w2T = (unsigned short*)alloc((size_t)NLAYER * DIM * FF * 2);
  float* bqkv = (float*)alloc((size_t)NLAYER * 1152 * 4);
  float* cosT = (float*)alloc((size_t)SEQ * HD * 4);
  float* sinT = (float*)alloc((size_t)SEQ * HD * 4);
  float* x = (float*)alloc((size_t)NB * SEQ * DIM * 4);
  unsigned short* hdn = (unsigned short*)alloc((size_t)NB * SEQ * DIM * 2);
  unsigned short* qpre = (unsigned short*)alloc((size_t)NB * SEQ * DIM * 2);
  unsigned short* kpre = (unsigned short*)alloc((size_t)NB * SEQ * DIM * 2);
  unsigned short* qb = (unsigned short*)alloc((size_t)NB * NH * SEQ * HDP * 2);
  unsigned short* kb = (unsigned short*)alloc((size_t)NB * NH * SEQ * HDP * 2);
  unsigned short* vtb = (unsigned short*)alloc((size_t)NB * NH * SEQ * HDP * 2);
  unsigned short* obuf = (unsigned short*)alloc((size_t)NB * SEQ * DIM * 2);
  unsigned short* a1 = (unsigned short*)alloc((size_t)NB * SEQ * FF * 2);
  int* dest = (int*)alloc((size_t)NB * SEQ * 4);

  // zero head-dim pad [48,64): q/k pads are contracted over by score MFMAs.
  hipMemsetAsync(qb, 0, (size_t)NB * NH * SEQ * HDP * 2, stream);
  hipMemsetAsync(kb, 0, (size_t)NB * NH * SEQ * HDP * 2, stream);

  dim3 tb(32, 8);
  wtrans_kernel<<<dim3(12, 12, 8), tb, 0, stream>>>(Wq, wqkvT, 384, 384, 147456, 442368);
  wtrans_kernel<<<dim3(12, 12, 8), tb, 0, stream>>>(Wk, wqkvT + 147456, 384, 384, 147456, 442368);
  wtrans_kernel<<<dim3(12, 12, 8), tb, 0, stream>>>(Wv, wqkvT + 294912, 384, 384, 147456, 442368);
  wtrans_kernel<<<dim3(12, 12, 8), tb, 0, stream>>>(Wo, woT, 384, 384, 147456, 147456);
  wtrans_kernel<<<dim3(48, 12, 8), tb, 0, stream>>>(W1, w1T, 384, 1536, 589824, 589824);
  wtrans_kernel<<<dim3(12, 48, 8), tb, 0, stream>>>(W2, w2T, 1536, 384, 589824, 589824);
  biascat_kernel<<<(NLAYER * 1152 + 255) / 256, 256, 0, stream>>>(bq, bk, bv, bqkv);
  ropetab_kernel<<<(SEQ * HD + 255) / 256, 256, 0, stream>>>(cosT, sinT);
  gatherrms_kernel<<<NB * SEQ / 4, 256, 0, stream>>>(vis, ids, mask_token, ln_in_w, x);

  for (int i = 0; i < NLAYER; i++) {
    size_t wo = (size_t)i * DIM * DIM;
    size_t wf = (size_t)i * DIM * FF;
    rmsbf_kernel<<<NB * SEQ / 4, 256, 0, stream>>>(x, ln1_w + i * DIM, hdn);
    gemm_kernel<<<dim3(64, 18), 256, 0, stream>>>(hdn, wqkvT + (size_t)i * 442368, bqkv + i * 1152,
                                                  NB * SEQ, 1152, DIM, 4, qpre, kpre, vtb, nullptr);
    rope_kernel<<<NB * SEQ, 384, 0, stream>>>(qpre, kpre, cosT, sinT, qb, kb);
    fattn_kernel<<<dim3(128, 16), 64, 0, stream>>>(qb, kb, vtb, obuf);
    gemm_kernel<<<dim3(64, 6), 256, 0, stream>>>(obuf, woT + wo, bo + i * DIM, NB * SEQ, DIM, DIM, 2,
                                                 nullptr, nullptr, nullptr, x);
    rmsbf_kernel<<<NB * SEQ / 4, 256, 0, stream>>>(x, ln2_w + i * DIM, hdn);
    gemm_kernel<<<dim3(64, 24), 256, 0, stream>>>(hdn, w1T + wf, b1 + i * FF, NB * SEQ, FF, DIM, 3,
                                                  a1, nullptr, nullptr, nullptr);
    gemm_kernel<<<dim3(64, 6), 256, 0, stream>>>(a1, w2T + wf, b2 + i * DIM, NB * SEQ, DIM, FF, 2,
                                                 nullptr, nullptr, nullptr, x);
  }
  rank_kernel<<<(NB * SEQ + 255) / 256, 256, 0, stream>>>(mask, dest);
  output_kernel<<<NB * SEQ * 96 / 256, 256, 0, stream>>>(x, dest, (float*)d_out);
}

// Round 3
// 1674.509 us; speedup vs baseline: 1.2288x; 1.0362x over previous
//
#include <hip/hip_runtime.h>

typedef __attribute__((ext_vector_type(8))) __bf16 bf16x8;
typedef __attribute__((ext_vector_type(8))) unsigned short ushort8;
typedef __attribute__((ext_vector_type(4))) float floatx4;

#define NB 2
#define SEQ 2048
#define DIM 384
#define NH 8
#define HD 48
#define HDP 64
#define FF 1536
#define NLAYER 8
#define ATT_SCALE 0.14433756729740643f  // 1/sqrt(48)

__device__ __forceinline__ unsigned short f2bf(float f) {
  unsigned u = __builtin_bit_cast(unsigned, f);
  u += 0x7fffu + ((u >> 16) & 1u);
  return (unsigned short)(u >> 16);
}
__device__ __forceinline__ float bf2f(unsigned short h) {
  unsigned u = ((unsigned)h) << 16;
  return __builtin_bit_cast(float, u);
}
__device__ __forceinline__ bf16x8 ldb8(const unsigned short* p) {
  return __builtin_bit_cast(bf16x8, *(const ushort8*)p);
}
__device__ __forceinline__ void gl2lds16(const unsigned short* g, unsigned short* l) {
  __builtin_amdgcn_global_load_lds((const __attribute__((address_space(1))) unsigned int*)g,
                                   (__attribute__((address_space(3))) unsigned int*)l, 16, 0, 0);
}
#define MFMA(a, b, c) __builtin_amdgcn_mfma_f32_16x16x32_bf16(a, b, c, 0, 0, 0)

// ---------------- weight transpose+convert: W (K x N) fp32 -> Wt (N x K) bf16 ----
__global__ __launch_bounds__(256) void wtrans_kernel(const float* __restrict__ W,
                                                     unsigned short* __restrict__ Wt,
                                                     int K, int N,
                                                     size_t sstride, size_t dstride) {
  __shared__ unsigned short tile[32][33];
  const float* Wl = W + (size_t)blockIdx.z * sstride;
  unsigned short* Wtl = Wt + (size_t)blockIdx.z * dstride;
  int n0 = blockIdx.x * 32, k0 = blockIdx.y * 32;
  int tx = threadIdx.x, ty = threadIdx.y;  // block (32,8)
  for (int i = ty; i < 32; i += 8)
    tile[i][tx] = f2bf(Wl[(size_t)(k0 + i) * N + n0 + tx]);
  __syncthreads();
  for (int i = ty; i < 32; i += 8)
    Wtl[(size_t)(n0 + i) * K + k0 + tx] = tile[tx][i];
}

// ---------------- qkv bias concat [8][1152] ----------------
__global__ void biascat_kernel(const float* __restrict__ bq, const float* __restrict__ bk,
                               const float* __restrict__ bv, float* __restrict__ out) {
  int idx = blockIdx.x * 256 + threadIdx.x;
  if (idx >= NLAYER * 1152) return;
  int z = idx / 1152, j = idx % 1152;
  float v = (j < 384) ? bq[z * 384 + j] : (j < 768) ? bk[z * 384 + j - 384] : bv[z * 384 + j - 768];
  out[idx] = v;
}

// ---------------- rope tables ----------------
__global__ void ropetab_kernel(float* __restrict__ cosT, float* __restrict__ sinT) {
  int idx = blockIdx.x * 256 + threadIdx.x;
  if (idx >= SEQ * HD) return;
  int l = idx / HD, d = idx % HD;
  int j = d % 24;
  float inv = powf(10000.0f, -(float)j / 24.0f);
  float pos;
  if (j < 6) pos = (float)(l >> 8);
  else if (j < 15) pos = (float)((l >> 4) & 15);
  else pos = (float)(l & 15);
  float f = pos * inv;
  cosT[idx] = cosf(f);
  sinT[idx] = sinf(f);
}

// ---------------- gather (ids_restore) + input RMS -> fp32 stream x ----------------
__global__ __launch_bounds__(256) void gatherrms_kernel(const float* __restrict__ vis,
                                                        const int* __restrict__ ids,
                                                        const float* __restrict__ mask_token,
                                                        const float* __restrict__ w,
                                                        float* __restrict__ x) {
  int wv = threadIdx.x >> 6, lane = threadIdx.x & 63;
  int row = blockIdx.x * 4 + wv;  // b*2048 + l
  int b = row >> 11;
  int src = ids[row];
  const float* p = (src < 512) ? (vis + ((size_t)b * 512 + src) * DIM) : mask_token;
  float v[6];
  float ss = 0.f;
#pragma unroll
  for (int j = 0; j < 6; j++) { v[j] = p[lane + 64 * j]; ss += v[j] * v[j]; }
#pragma unroll
  for (int m = 32; m; m >>= 1) ss += __shfl_xor(ss, m);
  float s = rsqrtf(ss * (1.0f / DIM) + 1e-6f);
#pragma unroll
  for (int j = 0; j < 6; j++)
    x[(size_t)row * DIM + lane + 64 * j] = v[j] * s * w[lane + 64 * j];
}

// ---------------- RMS (fp32 in) -> bf16 out ----------------
__global__ __launch_bounds__(256) void rmsbf_kernel(const float* __restrict__ x,
                                                    const float* __restrict__ w,
                                                    unsigned short* __restrict__ out) {
  int wv = threadIdx.x >> 6, lane = threadIdx.x & 63;
  int row = blockIdx.x * 4 + wv;
  const float* xr = x + (size_t)row * DIM;
  float v[6];
  float ss = 0.f;
#pragma unroll
  for (int j = 0; j < 6; j++) { v[j] = xr[lane + 64 * j]; ss += v[j] * v[j]; }
#pragma unroll
  for (int m = 32; m; m >>= 1) ss += __shfl_xor(ss, m);
  float s = rsqrtf(ss * (1.0f / DIM) + 1e-6f);
#pragma unroll
  for (int j = 0; j < 6; j++)
    out[(size_t)row * DIM + lane + 64 * j] = f2bf(v[j] * s * w[lane + 64 * j]);
}

// ============ epilogue writer shared by both GEMMs ============
__device__ __forceinline__ void gemm_store(int mode, int rg, int cg, float v, int N,
                                           unsigned short* outb, unsigned short* outb2,
                                           unsigned short* outv, float* outf) {
  if (mode == 2) {
    outf[(size_t)rg * N + cg] += v;
  } else if (mode == 3) {
    float g = v * 0.5f * (1.0f + erff(v * 0.70710678f));
    outb[(size_t)rg * N + cg] = f2bf(g);
  } else {  // mode 4: qkv split
    if (cg < 384) {
      outb[(size_t)rg * 384 + cg] = f2bf(v);
    } else if (cg < 768) {
      outb2[(size_t)rg * 384 + cg - 384] = f2bf(v);
    } else {
      int j = cg - 768;
      int h = j / HD, hd = j % HD;
      int b = rg >> 11, l = rg & 2047;
      outv[(((size_t)b * NH + h) * HDP + hd) * SEQ + l] = f2bf(v);
    }
  }
}

// ---------------- 64x64-tile GEMM (LDS staged via VGPR) ----------------
__global__ __launch_bounds__(256) void gemm_kernel(const unsigned short* __restrict__ A,
                                                   const unsigned short* __restrict__ Wt,
                                                   const float* __restrict__ bias,
                                                   int M, int N, int K, int mode,
                                                   unsigned short* __restrict__ outb,
                                                   unsigned short* __restrict__ outb2,
                                                   unsigned short* __restrict__ outv,
                                                   float* __restrict__ outf) {
  __shared__ __align__(16) unsigned short As[64][40];
  __shared__ __align__(16) unsigned short Bs[64][40];
  int tid = threadIdx.x;
  int wv = tid >> 6, lane = tid & 63;
  int wm = wv >> 1, wn = wv & 1;
  int row0 = blockIdx.x * 64, col0 = blockIdx.y * 64;
  int q = lane >> 4, c = lane & 15;
  floatx4 acc[2][2] = {};
  int srow = tid >> 2, sk = (tid & 3) * 8;
  const unsigned short* Ap = A + (size_t)(row0 + srow) * K + sk;
  const unsigned short* Bp = Wt + (size_t)(col0 + srow) * K + sk;
  for (int k0 = 0; k0 < K; k0 += 32) {
    *(ushort8*)(&As[srow][sk]) = *(const ushort8*)(Ap + k0);
    *(ushort8*)(&Bs[srow][sk]) = *(const ushort8*)(Bp + k0);
    __syncthreads();
    bf16x8 a0 = ldb8(&As[wm * 32 + c][q * 8]);
    bf16x8 a1 = ldb8(&As[wm * 32 + 16 + c][q * 8]);
    bf16x8 b0 = ldb8(&Bs[wn * 32 + c][q * 8]);
    bf16x8 b1 = ldb8(&Bs[wn * 32 + 16 + c][q * 8]);
    acc[0][0] = MFMA(a0, b0, acc[0][0]);
    acc[0][1] = MFMA(a0, b1, acc[0][1]);
    acc[1][0] = MFMA(a1, b0, acc[1][0]);
    acc[1][1] = MFMA(a1, b1, acc[1][1]);
    __syncthreads();
  }
#pragma unroll
  for (int tm = 0; tm < 2; tm++)
#pragma unroll
    for (int tn = 0; tn < 2; tn++)
#pragma unroll
      for (int r = 0; r < 4; r++) {
        int rg = row0 + wm * 32 + tm * 16 + q * 4 + r;
        int cg = col0 + wn * 32 + tn * 16 + c;
        gemm_store(mode, rg, cg, acc[tm][tn][r] + bias[cg], N, outb, outb2, outv, outf);
      }
}

// ---------------- 128x128-tile GEMM, global_load_lds width-16 staging (m97 structure) ------
__global__ __launch_bounds__(256) void gemm128_kernel(const unsigned short* __restrict__ A,
                                                      const unsigned short* __restrict__ Wt,
                                                      const float* __restrict__ bias,
                                                      int M, int N, int K, int mode,
                                                      unsigned short* __restrict__ outb,
                                                      unsigned short* __restrict__ outb2,
                                                      unsigned short* __restrict__ outv,
                                                      float* __restrict__ outf) {
  __shared__ __align__(16) unsigned short As[128 * 32];
  __shared__ __align__(16) unsigned short Bs[128 * 32];
  int tid = threadIdx.x;
  int wv = tid >> 6, lane = tid & 63;
  int q = lane >> 4, c = lane & 15;
  int wm = wv >> 1, wn = wv & 1;
  int row0 = blockIdx.x * 128, col0 = blockIdx.y * 128;
  floatx4 acc[4][4] = {};
  int sr = tid >> 2, sk = (tid & 3) * 8;
  const unsigned short* Ag = A + (size_t)(row0 + sr) * K + sk;
  const unsigned short* Bg = Wt + (size_t)(col0 + sr) * K + sk;
  unsigned short* Asl = As + tid * 8;
  unsigned short* Bsl = Bs + tid * 8;
  for (int k0 = 0; k0 < K; k0 += 32) {
    gl2lds16(Ag + k0, Asl);
    gl2lds16(Ag + (size_t)64 * K + k0, Asl + 2048);
    gl2lds16(Bg + k0, Bsl);
    gl2lds16(Bg + (size_t)64 * K + k0, Bsl + 2048);
    __syncthreads();
    bf16x8 af[4], bfr[4];
#pragma unroll
    for (int mt = 0; mt < 4; mt++) af[mt] = ldb8(&As[(wm * 64 + mt * 16 + c) * 32 + q * 8]);
#pragma unroll
    for (int nt = 0; nt < 4; nt++) bfr[nt] = ldb8(&Bs[(wn * 64 + nt * 16 + c) * 32 + q * 8]);
#pragma unroll
    for (int mt = 0; mt < 4; mt++)
#pragma unroll
      for (int nt = 0; nt < 4; nt++) acc[mt][nt] = MFMA(af[mt], bfr[nt], acc[mt][nt]);
    __syncthreads();
  }
#pragma unroll
  for (int mt = 0; mt < 4; mt++)
#pragma unroll
    for (int nt = 0; nt < 4; nt++)
#pragma unroll
      for (int r = 0; r < 4; r++) {
        int rg = row0 + wm * 64 + mt * 16 + q * 4 + r;
        int cg = col0 + wn * 64 + nt * 16 + c;
        gemm_store(mode, rg, cg, acc[mt][nt][r] + bias[cg], N, outb, outb2, outv, outf);
      }
}

// ---------------- rope: qpre/kpre (bf16 row-major) -> q/k [b][h][l][64]; q scaled ----------
__global__ __launch_bounds__(384) void rope_kernel(const unsigned short* __restrict__ qpre,
                                                   const unsigned short* __restrict__ kpre,
                                                   const float* __restrict__ cosT,
                                                   const float* __restrict__ sinT,
                                                   unsigned short* __restrict__ qdst,
                                                   unsigned short* __restrict__ kdst) {
  int row = blockIdx.x;  // b*2048 + l
  int b = row >> 11, l = row & 2047;
  int t = threadIdx.x;
  const unsigned short* src = (t >= 192) ? kpre : qpre;
  unsigned short* dst = (t >= 192) ? kdst : qdst;
  float sc = (t >= 192) ? 1.0f : ATT_SCALE;  // fold 1/sqrt(hd) into q
  int pp = t % 192;
  int h = pp / 24, d = pp % 24;
  float x1 = bf2f(src[(size_t)row * DIM + h * HD + d]);
  float x2 = bf2f(src[(size_t)row * DIM + h * HD + d + 24]);
  float cs = cosT[l * HD + d], sn = sinT[l * HD + d];
  size_t base = (((size_t)b * NH + h) * SEQ + l) * HDP;
  dst[base + d] = f2bf((x1 * cs - x2 * sn) * sc);
  dst[base + d + 24] = f2bf((x2 * cs + x1 * sn) * sc);
}

// ---------------- flash attention, 4-wave K-split per block ----------------
// block = (q-tile of 16 rows, bh); wave w handles k-tiles kstart+w*64, +256, ...
// Online softmax per wave in regs; cross-wave combine via LDS (m/l merge + scaled-O sum).
__global__ __launch_bounds__(256, 4) void fattn_kernel(const unsigned short* __restrict__ qb,
                                                       const unsigned short* __restrict__ kb,
                                                       const unsigned short* __restrict__ vt,
                                                       unsigned short* __restrict__ obuf) {
  __shared__ __align__(16) unsigned short Pt[4][16][72];
  __shared__ float Os[4 * 16 * 49];
  __shared__ float Lm[4][16], Ll[4][16], Linv[16];
  int tid = threadIdx.x;
  int wv = tid >> 6, lane = tid & 63;
  int q = lane >> 4, c = lane & 15;
  int bh = blockIdx.y;
  int q0 = blockIdx.x * 16;
  int kstart = q0 & ~255;  // frame-aligned reverse-causal mask
  const unsigned short* qbase = qb + (size_t)bh * SEQ * HDP;
  const unsigned short* kbase = kb + (size_t)bh * SEQ * HDP;
  const unsigned short* vbase = vt + (size_t)bh * HDP * SEQ;
  bf16x8 a0 = ldb8(qbase + (size_t)(q0 + c) * HDP + q * 8);
  bf16x8 a1 = ldb8(qbase + (size_t)(q0 + c) * HDP + 32 + q * 8);
  floatx4 O[3] = {};
  float mr[4] = {-3e38f, -3e38f, -3e38f, -3e38f};
  float lr[4] = {0.f, 0.f, 0.f, 0.f};
  for (int k0 = kstart + wv * 64; k0 < SEQ; k0 += 256) {
    floatx4 S[4];
#pragma unroll
    for (int t = 0; t < 4; t++) {
      const unsigned short* krow = kbase + (size_t)(k0 + t * 16 + c) * HDP;
      bf16x8 b0 = ldb8(krow + q * 8);
      bf16x8 b1 = ldb8(krow + 32 + q * 8);
      floatx4 z = {};
      z = MFMA(a0, b0, z);
      S[t] = MFMA(a1, b1, z);
    }
    float alpha[4];
#pragma unroll
    for (int r = 0; r < 4; r++) {
      float m0 = fmaxf(fmaxf(S[0][r], S[1][r]), fmaxf(S[2][r], S[3][r]));
#pragma unroll
      for (int msk = 1; msk < 16; msk <<= 1) m0 = fmaxf(m0, __shfl_xor(m0, msk, 16));
      float nm = fmaxf(mr[r], m0);
      alpha[r] = __expf(mr[r] - nm);
      mr[r] = nm;
      lr[r] *= alpha[r];
    }
#pragma unroll
    for (int t = 0; t < 4; t++)
#pragma unroll
      for (int r = 0; r < 4; r++) {
        float pv = __expf(S[t][r] - mr[r]);
        lr[r] += pv;
        Pt[wv][q * 4 + r][t * 16 + c] = f2bf(pv);
      }
#pragma unroll
    for (int f = 0; f < 3; f++)
#pragma unroll
      for (int r = 0; r < 4; r++) O[f][r] *= alpha[r];
    bf16x8 pa0 = ldb8(&Pt[wv][c][q * 8]);
    bf16x8 pa1 = ldb8(&Pt[wv][c][32 + q * 8]);
#pragma unroll
    for (int f = 0; f < 3; f++) {
      const unsigned short* vrow = vbase + (size_t)(f * 16 + c) * SEQ + k0;
      bf16x8 v0 = ldb8(vrow + q * 8);
      bf16x8 v1 = ldb8(vrow + 32 + q * 8);
      O[f] = MFMA(pa0, v0, O[f]);
      O[f] = MFMA(pa1, v1, O[f]);
    }
  }
  // reduce l over the 16 lanes of each row
#pragma unroll
  for (int r = 0; r < 4; r++) {
#pragma unroll
    for (int msk = 1; msk < 16; msk <<= 1) lr[r] += __shfl_xor(lr[r], msk, 16);
  }
  if (c == 0) {
#pragma unroll
    for (int r = 0; r < 4; r++) {
      Lm[wv][q * 4 + r] = mr[r];
      Ll[wv][q * 4 + r] = lr[r];
    }
  }
  __syncthreads();
  // merge per-wave stats; scale own O; deposit to LDS
#pragma unroll
  for (int r = 0; r < 4; r++) {
    int row = q * 4 + r;
    float m0 = Lm[0][row], m1 = Lm[1][row], m2 = Lm[2][row], m3 = Lm[3][row];
    float M = fmaxf(fmaxf(m0, m1), fmaxf(m2, m3));
    float Lt = Ll[0][row] * __expf(m0 - M) + Ll[1][row] * __expf(m1 - M) +
               Ll[2][row] * __expf(m2 - M) + Ll[3][row] * __expf(m3 - M);
    float myf = __expf(mr[r] - M);
    if (wv == 0 && c == 0) Linv[row] = 1.0f / Lt;
#pragma unroll
    for (int f = 0; f < 3; f++)
      Os[(wv * 16 + row) * 49 + f * 16 + c] = O[f][r] * myf;
  }
  __syncthreads();
  if (wv < 3) {
    int b = bh >> 3, h = bh & 7;
#pragma unroll
    for (int r = 0; r < 4; r++) {
      int row = q * 4 + r;
      float s = Os[(0 * 16 + row) * 49 + wv * 16 + c] + Os[(1 * 16 + row) * 49 + wv * 16 + c] +
                Os[(2 * 16 + row) * 49 + wv * 16 + c] + Os[(3 * 16 + row) * 49 + wv * 16 + c];
      obuf[((size_t)b * SEQ + q0 + row) * DIM + h * HD + wv * 16 + c] = f2bf(s * Linv[row]);
    }
  }
}

// ---------------- stable argsort(-mask) ranks -> dest row in [0,2048) ----------------
__global__ void rank_kernel(const int* __restrict__ mask, int* __restrict__ dest) {
  int idx = blockIdx.x * 256 + threadIdx.x;
  if (idx >= NB * SEQ) return;
  int b = idx >> 11, l = idx & 2047;
  const int* mb = mask + b * SEQ;
  int p1 = 0;
  for (int j = 0; j < l; j++) p1 += mb[j];
  dest[idx] = mb[l] ? p1 : 512 + (l - p1);
}

// ---------------- write decoded_full + scattered visible/masked ----------------
__global__ __launch_bounds__(256) void output_kernel(const float* __restrict__ x,
                                                     const int* __restrict__ dest,
                                                     float* __restrict__ out) {
  int idx = blockIdx.x * 256 + threadIdx.x;  // NB*SEQ*96
  int row = idx / 96, c = idx % 96;
  float4 v = ((const float4*)(x + (size_t)row * DIM))[c];
  ((float4*)(out + (size_t)row * DIM))[c] = v;
  int b = row >> 11;
  int d = dest[row];
  size_t base = (size_t)NB * SEQ * DIM;
  size_t o;
  if (d < 512) o = base + ((size_t)b * 512 + d) * DIM;
  else o = base + (size_t)NB * 512 * DIM + ((size_t)b * 1536 + (d - 512)) * DIM;
  ((float4*)(out + o))[c] = v;
}

extern "C" void kernel_launch(void* const* d_in, const int* in_sizes, int n_in,
                              void* d_out, int out_size, void* d_ws, size_t ws_size,
                              hipStream_t stream) {
  const float* vis = (const float*)d_in[0];
  const int* ids = (const int*)d_in[1];
  const int* mask = (const int*)d_in[2];
  const float* mask_token = (const float*)d_in[6];
  const float* ln_in_w = (const float*)d_in[7];
  const float* ln1_w = (const float*)d_in[8];
  const float* ln2_w = (const float*)d_in[9];
  const float* Wq = (const float*)d_in[10];
  const float* bq = (const float*)d_in[11];
  const float* Wk = (const float*)d_in[12];
  const float* bk = (const float*)d_in[13];
  const float* Wv = (const float*)d_in[14];
  const float* bv = (const float*)d_in[15];
  const float* Wo = (const float*)d_in[16];
  const float* bo = (const float*)d_in[17];
  const float* W1 = (const float*)d_in[18];
  const float* b1 = (const float*)d_in[19];
  const float* W2 = (const float*)d_in[20];
  const float* b2 = (const float*)d_in[21];

  char* p = (char*)d_ws;
  size_t off = 0;
  auto alloc = [&](size_t n) -> void* {
    off = (off + 255) & ~(size_t)255;
    void* r = p + off;
    off += n;
    return r;
  };
  unsigned short* wqkvT = (unsigned short*)alloc((size_t)NLAYER * 1152 * DIM * 2);
  unsigned short* woT = (unsigned short*)alloc((size_t)NLAYER * DIM * DIM * 2);
  unsigned short* w1T = (unsigned short*)alloc((size_t)NLAYER * DIM * FF * 2);
  unsigned short* w2T = (unsigned short*)alloc((size_t)NLAYER * DIM * FF * 2);
  float* bqkv = (float*)alloc((size_t)NLAYER * 1152 * 4);
  float* cosT = (float*)alloc((size_t)SEQ * HD * 4);
  float* sinT = (float*)alloc((size_t)SEQ * HD * 4);
  float* x = (float*)alloc((size_t)NB * SEQ * DIM * 4);
  unsigned short* hdn = (unsigned short*)alloc((size_t)NB * SEQ * DIM * 2);
  unsigned short* qpre = (unsigned short*)alloc((size_t)NB * SEQ * DIM * 2);
  unsigned short* kpre = (unsigned short*)alloc((size_t)NB * SEQ * DIM * 2);
  unsigned short* qb = (unsigned short*)alloc((size_t)NB * NH * SEQ * HDP * 2);
  unsigned short* kb = (unsigned short*)alloc((size_t)NB * NH * SEQ * HDP * 2);
  unsigned short* vtb = (unsigned short*)alloc((size_t)NB * NH * SEQ * HDP * 2);
  unsigned short* obuf = (unsigned short*)alloc((size_t)NB * SEQ * DIM * 2);
  unsigned short* a1 = (unsigned short*)alloc((size_t)NB * SEQ * FF * 2);
  int* dest = (int*)alloc((size_t)NB * SEQ * 4);

  // zero head-dim pad [48,64): q/k pads are contracted over by score MFMAs.
  hipMemsetAsync(qb, 0, (size_t)NB * NH * SEQ * HDP * 2, stream);
  hipMemsetAsync(kb, 0, (size_t)NB * NH * SEQ * HDP * 2, stream);

  dim3 tb(32, 8);
  wtrans_kernel<<<dim3(12, 12, 8), tb, 0, stream>>>(Wq, wqkvT, 384, 384, 147456, 442368);
  wtrans_kernel<<<dim3(12, 12, 8), tb, 0, stream>>>(Wk, wqkvT + 147456, 384, 384, 147456, 442368);
  wtrans_kernel<<<dim3(12, 12, 8), tb, 0, stream>>>(Wv, wqkvT + 294912, 384, 384, 147456, 442368);
  wtrans_kernel<<<dim3(12, 12, 8), tb, 0, stream>>>(Wo, woT, 384, 384, 147456, 147456);
  wtrans_kernel<<<dim3(48, 12, 8), tb, 0, stream>>>(W1, w1T, 384, 1536, 589824, 589824);
  wtrans_kernel<<<dim3(12, 48, 8), tb, 0, stream>>>(W2, w2T, 1536, 384, 589824, 589824);
  biascat_kernel<<<(NLAYER * 1152 + 255) / 256, 256, 0, stream>>>(bq, bk, bv, bqkv);
  ropetab_kernel<<<(SEQ * HD + 255) / 256, 256, 0, stream>>>(cosT, sinT);
  gatherrms_kernel<<<NB * SEQ / 4, 256, 0, stream>>>(vis, ids, mask_token, ln_in_w, x);

  for (int i = 0; i < NLAYER; i++) {
    size_t wo = (size_t)i * DIM * DIM;
    size_t wf = (size_t)i * DIM * FF;
    rmsbf_kernel<<<NB * SEQ / 4, 256, 0, stream>>>(x, ln1_w + i * DIM, hdn);
    gemm128_kernel<<<dim3(32, 9), 256, 0, stream>>>(hdn, wqkvT + (size_t)i * 442368, bqkv + i * 1152,
                                                    NB * SEQ, 1152, DIM, 4, qpre, kpre, vtb, nullptr);
    rope_kernel<<<NB * SEQ, 384, 0, stream>>>(qpre, kpre, cosT, sinT, qb, kb);
    fattn_kernel<<<dim3(128, 16), 256, 0, stream>>>(qb, kb, vtb, obuf);
    gemm_kernel<<<dim3(64, 6), 256, 0, stream>>>(obuf, woT + wo, bo + i * DIM, NB * SEQ, DIM, DIM, 2,
                                                 nullptr, nullptr, nullptr, x);
    rmsbf_kernel<<<NB * SEQ / 4, 256, 0, stream>>>(x, ln2_w + i * DIM, hdn);
    gemm128_kernel<<<dim3(32, 12), 256, 0, stream>>>(hdn, w1T + wf, b1 + i * FF, NB * SEQ, FF, DIM, 3,
                                                     a1, nullptr, nullptr, nullptr);
    gemm_kernel<<<dim3(64, 6), 256, 0, stream>>>(a1, w2T + wf, b2 + i * DIM, NB * SEQ, DIM, FF, 2,
                                                 nullptr, nullptr, nullptr, x);
  }
  rank_kernel<<<(NB * SEQ + 255) / 256, 256, 0, stream>>>(mask, dest);
  output_kernel<<<NB * SEQ * 96 / 256, 256, 0, stream>>>(x, dest, (float*)d_out);
}

// Round 4
// 1332.566 us; speedup vs baseline: 1.5442x; 1.2566x over previous
//
#include <hip/hip_runtime.h>

typedef __attribute__((ext_vector_type(8))) __bf16 bf16x8;
typedef __attribute__((ext_vector_type(8))) unsigned short ushort8;
typedef __attribute__((ext_vector_type(4))) float floatx4;

#define NB 2
#define SEQ 2048
#define DIM 384
#define NH 8
#define HD 48
#define HDP 64
#define FF 1536
#define NLAYER 8
#define ATT_SCALE 0.14433756729740643f  // 1/sqrt(48)

__device__ __forceinline__ unsigned short f2bf(float f) {
  unsigned u = __builtin_bit_cast(unsigned, f);
  u += 0x7fffu + ((u >> 16) & 1u);
  return (unsigned short)(u >> 16);
}
__device__ __forceinline__ float bf2f(unsigned short h) {
  unsigned u = ((unsigned)h) << 16;
  return __builtin_bit_cast(float, u);
}
__device__ __forceinline__ bf16x8 ldb8(const unsigned short* p) {
  return __builtin_bit_cast(bf16x8, *(const ushort8*)p);
}
__device__ __forceinline__ void gl2lds16(const unsigned short* g, unsigned short* l) {
  __builtin_amdgcn_global_load_lds((const __attribute__((address_space(1))) unsigned int*)g,
                                   (__attribute__((address_space(3))) unsigned int*)l, 16, 0, 0);
}
#define MFMA(a, b, c) __builtin_amdgcn_mfma_f32_16x16x32_bf16(a, b, c, 0, 0, 0)

// ---------------- weight transpose+convert: W (K x N) fp32 -> Wt (N x K) bf16 ----
__global__ __launch_bounds__(256) void wtrans_kernel(const float* __restrict__ W,
                                                     unsigned short* __restrict__ Wt,
                                                     int K, int N,
                                                     size_t sstride, size_t dstride) {
  __shared__ unsigned short tile[32][33];
  const float* Wl = W + (size_t)blockIdx.z * sstride;
  unsigned short* Wtl = Wt + (size_t)blockIdx.z * dstride;
  int n0 = blockIdx.x * 32, k0 = blockIdx.y * 32;
  int tx = threadIdx.x, ty = threadIdx.y;  // block (32,8)
  for (int i = ty; i < 32; i += 8)
    tile[i][tx] = f2bf(Wl[(size_t)(k0 + i) * N + n0 + tx]);
  __syncthreads();
  for (int i = ty; i < 32; i += 8)
    Wtl[(size_t)(n0 + i) * K + k0 + tx] = tile[tx][i];
}

// ---------------- qkv bias concat [8][1152] ----------------
__global__ void biascat_kernel(const float* __restrict__ bq, const float* __restrict__ bk,
                               const float* __restrict__ bv, float* __restrict__ out) {
  int idx = blockIdx.x * 256 + threadIdx.x;
  if (idx >= NLAYER * 1152) return;
  int z = idx / 1152, j = idx % 1152;
  float v = (j < 384) ? bq[z * 384 + j] : (j < 768) ? bk[z * 384 + j - 384] : bv[z * 384 + j - 768];
  out[idx] = v;
}

// ---------------- rope tables ----------------
__global__ void ropetab_kernel(float* __restrict__ cosT, float* __restrict__ sinT) {
  int idx = blockIdx.x * 256 + threadIdx.x;
  if (idx >= SEQ * HD) return;
  int l = idx / HD, d = idx % HD;
  int j = d % 24;
  float inv = powf(10000.0f, -(float)j / 24.0f);
  float pos;
  if (j < 6) pos = (float)(l >> 8);
  else if (j < 15) pos = (float)((l >> 4) & 15);
  else pos = (float)(l & 15);
  float f = pos * inv;
  cosT[idx] = cosf(f);
  sinT[idx] = sinf(f);
}

// ---------------- gather (ids_restore) + input RMS -> fp32 stream x ----------------
__global__ __launch_bounds__(256) void gatherrms_kernel(const float* __restrict__ vis,
                                                        const int* __restrict__ ids,
                                                        const float* __restrict__ mask_token,
                                                        const float* __restrict__ w,
                                                        float* __restrict__ x) {
  int wv = threadIdx.x >> 6, lane = threadIdx.x & 63;
  int row = blockIdx.x * 4 + wv;  // b*2048 + l
  int b = row >> 11;
  int src = ids[row];
  const float* p = (src < 512) ? (vis + ((size_t)b * 512 + src) * DIM) : mask_token;
  float v[6];
  float ss = 0.f;
#pragma unroll
  for (int j = 0; j < 6; j++) { v[j] = p[lane + 64 * j]; ss += v[j] * v[j]; }
#pragma unroll
  for (int m = 32; m; m >>= 1) ss += __shfl_xor(ss, m);
  float s = rsqrtf(ss * (1.0f / DIM) + 1e-6f);
#pragma unroll
  for (int j = 0; j < 6; j++)
    x[(size_t)row * DIM + lane + 64 * j] = v[j] * s * w[lane + 64 * j];
}

// ---------------- RMS (fp32 in) -> bf16 out ----------------
__global__ __launch_bounds__(256) void rmsbf_kernel(const float* __restrict__ x,
                                                    const float* __restrict__ w,
                                                    unsigned short* __restrict__ out) {
  int wv = threadIdx.x >> 6, lane = threadIdx.x & 63;
  int row = blockIdx.x * 4 + wv;
  const float* xr = x + (size_t)row * DIM;
  float v[6];
  float ss = 0.f;
#pragma unroll
  for (int j = 0; j < 6; j++) { v[j] = xr[lane + 64 * j]; ss += v[j] * v[j]; }
#pragma unroll
  for (int m = 32; m; m >>= 1) ss += __shfl_xor(ss, m);
  float s = rsqrtf(ss * (1.0f / DIM) + 1e-6f);
#pragma unroll
  for (int j = 0; j < 6; j++)
    out[(size_t)row * DIM + lane + 64 * j] = f2bf(v[j] * s * w[lane + 64 * j]);
}

// ============ epilogue writer shared by both GEMMs ============
__device__ __forceinline__ void gemm_store(int mode, int rg, int cg, float v, int N,
                                           unsigned short* outb, unsigned short* outb2,
                                           unsigned short* outv, float* outf) {
  if (mode == 2) {
    outf[(size_t)rg * N + cg] += v;
  } else if (mode == 3) {
    float g = v * 0.5f * (1.0f + erff(v * 0.70710678f));
    outb[(size_t)rg * N + cg] = f2bf(g);
  } else {  // mode 4: qkv split
    if (cg < 384) {
      outb[(size_t)rg * 384 + cg] = f2bf(v);
    } else if (cg < 768) {
      outb2[(size_t)rg * 384 + cg - 384] = f2bf(v);
    } else {
      int j = cg - 768;
      int h = j / HD, hd = j % HD;
      int b = rg >> 11, l = rg & 2047;
      outv[(((size_t)b * NH + h) * HDP + hd) * SEQ + l] = f2bf(v);
    }
  }
}

// ---------------- 64x64-tile GEMM (LDS staged via VGPR) ----------------
__global__ __launch_bounds__(256) void gemm_kernel(const unsigned short* __restrict__ A,
                                                   const unsigned short* __restrict__ Wt,
                                                   const float* __restrict__ bias,
                                                   int M, int N, int K, int mode,
                                                   unsigned short* __restrict__ outb,
                                                   unsigned short* __restrict__ outb2,
                                                   unsigned short* __restrict__ outv,
                                                   float* __restrict__ outf) {
  __shared__ __align__(16) unsigned short As[64][40];
  __shared__ __align__(16) unsigned short Bs[64][40];
  int tid = threadIdx.x;
  int wv = tid >> 6, lane = tid & 63;
  int wm = wv >> 1, wn = wv & 1;
  int row0 = blockIdx.x * 64, col0 = blockIdx.y * 64;
  int q = lane >> 4, c = lane & 15;
  floatx4 acc[2][2] = {};
  int srow = tid >> 2, sk = (tid & 3) * 8;
  const unsigned short* Ap = A + (size_t)(row0 + srow) * K + sk;
  const unsigned short* Bp = Wt + (size_t)(col0 + srow) * K + sk;
  for (int k0 = 0; k0 < K; k0 += 32) {
    *(ushort8*)(&As[srow][sk]) = *(const ushort8*)(Ap + k0);
    *(ushort8*)(&Bs[srow][sk]) = *(const ushort8*)(Bp + k0);
    __syncthreads();
    bf16x8 a0 = ldb8(&As[wm * 32 + c][q * 8]);
    bf16x8 a1 = ldb8(&As[wm * 32 + 16 + c][q * 8]);
    bf16x8 b0 = ldb8(&Bs[wn * 32 + c][q * 8]);
    bf16x8 b1 = ldb8(&Bs[wn * 32 + 16 + c][q * 8]);
    acc[0][0] = MFMA(a0, b0, acc[0][0]);
    acc[0][1] = MFMA(a0, b1, acc[0][1]);
    acc[1][0] = MFMA(a1, b0, acc[1][0]);
    acc[1][1] = MFMA(a1, b1, acc[1][1]);
    __syncthreads();
  }
#pragma unroll
  for (int tm = 0; tm < 2; tm++)
#pragma unroll
    for (int tn = 0; tn < 2; tn++)
#pragma unroll
      for (int r = 0; r < 4; r++) {
        int rg = row0 + wm * 32 + tm * 16 + q * 4 + r;
        int cg = col0 + wn * 32 + tn * 16 + c;
        gemm_store(mode, rg, cg, acc[tm][tn][r] + bias[cg], N, outb, outb2, outv, outf);
      }
}

// ---------------- 128x128-tile GEMM, global_load_lds width-16 staging (m97 structure) ------
__global__ __launch_bounds__(256) void gemm128_kernel(const unsigned short* __restrict__ A,
                                                      const unsigned short* __restrict__ Wt,
                                                      const float* __restrict__ bias,
                                                      int M, int N, int K, int mode,
                                                      unsigned short* __restrict__ outb,
                                                      unsigned short* __restrict__ outb2,
                                                      unsigned short* __restrict__ outv,
                                                      float* __restrict__ outf) {
  __shared__ __align__(16) unsigned short As[128 * 32];
  __shared__ __align__(16) unsigned short Bs[128 * 32];
  int tid = threadIdx.x;
  int wv = tid >> 6, lane = tid & 63;
  int q = lane >> 4, c = lane & 15;
  int wm = wv >> 1, wn = wv & 1;
  int row0 = blockIdx.x * 128, col0 = blockIdx.y * 128;
  floatx4 acc[4][4] = {};
  int sr = tid >> 2, sk = (tid & 3) * 8;
  const unsigned short* Ag = A + (size_t)(row0 + sr) * K + sk;
  const unsigned short* Bg = Wt + (size_t)(col0 + sr) * K + sk;
  unsigned short* Asl = As + tid * 8;
  unsigned short* Bsl = Bs + tid * 8;
  for (int k0 = 0; k0 < K; k0 += 32) {
    gl2lds16(Ag + k0, Asl);
    gl2lds16(Ag + (size_t)64 * K + k0, Asl + 2048);
    gl2lds16(Bg + k0, Bsl);
    gl2lds16(Bg + (size_t)64 * K + k0, Bsl + 2048);
    __syncthreads();
    bf16x8 af[4], bfr[4];
#pragma unroll
    for (int mt = 0; mt < 4; mt++) af[mt] = ldb8(&As[(wm * 64 + mt * 16 + c) * 32 + q * 8]);
#pragma unroll
    for (int nt = 0; nt < 4; nt++) bfr[nt] = ldb8(&Bs[(wn * 64 + nt * 16 + c) * 32 + q * 8]);
#pragma unroll
    for (int mt = 0; mt < 4; mt++)
#pragma unroll
      for (int nt = 0; nt < 4; nt++) acc[mt][nt] = MFMA(af[mt], bfr[nt], acc[mt][nt]);
    __syncthreads();
  }
#pragma unroll
  for (int mt = 0; mt < 4; mt++)
#pragma unroll
    for (int nt = 0; nt < 4; nt++)
#pragma unroll
      for (int r = 0; r < 4; r++) {
        int rg = row0 + wm * 64 + mt * 16 + q * 4 + r;
        int cg = col0 + wn * 64 + nt * 16 + c;
        gemm_store(mode, rg, cg, acc[mt][nt][r] + bias[cg], N, outb, outb2, outv, outf);
      }
}

// ---------------- rope: qpre/kpre (bf16 row-major) -> q/k [b][h][l][64]; q scaled ----------
__global__ __launch_bounds__(384) void rope_kernel(const unsigned short* __restrict__ qpre,
                                                   const unsigned short* __restrict__ kpre,
                                                   const float* __restrict__ cosT,
                                                   const float* __restrict__ sinT,
                                                   unsigned short* __restrict__ qdst,
                                                   unsigned short* __restrict__ kdst) {
  int row = blockIdx.x;  // b*2048 + l
  int b = row >> 11, l = row & 2047;
  int t = threadIdx.x;
  const unsigned short* src = (t >= 192) ? kpre : qpre;
  unsigned short* dst = (t >= 192) ? kdst : qdst;
  float sc = (t >= 192) ? 1.0f : ATT_SCALE;  // fold 1/sqrt(hd) into q
  int pp = t % 192;
  int h = pp / 24, d = pp % 24;
  float x1 = bf2f(src[(size_t)row * DIM + h * HD + d]);
  float x2 = bf2f(src[(size_t)row * DIM + h * HD + d + 24]);
  float cs = cosT[l * HD + d], sn = sinT[l * HD + d];
  size_t base = (((size_t)b * NH + h) * SEQ + l) * HDP;
  dst[base + d] = f2bf((x1 * cs - x2 * sn) * sc);
  dst[base + d + 24] = f2bf((x2 * cs + x1 * sn) * sc);
}

// ---------------- flash attention v3: 64 q-rows/block, LDS-shared K/V tiles ----------------
// 4 waves, wave wv owns q-rows q0+wv*16..+16 (full rows: online softmax, no combine).
// K-tile 64x64 and V-tile 48x64 staged to padded LDS, reused by all 4 waves.
// XCD-aware decode: bh = 2*(i&7)+((i>>3)&1) keeps each XCD on 2 heads (K/V fits its L2).
__global__ __launch_bounds__(256) void fattn_kernel(const unsigned short* __restrict__ qb,
                                                    const unsigned short* __restrict__ kb,
                                                    const unsigned short* __restrict__ vt,
                                                    unsigned short* __restrict__ obuf) {
  __shared__ __align__(16) unsigned short Ks[64][72];
  __shared__ __align__(16) unsigned short Vs[48][72];
  __shared__ __align__(16) unsigned short Pt[4][16][72];
  int tid = threadIdx.x;
  int wv = tid >> 6, lane = tid & 63;
  int q = lane >> 4, c = lane & 15;
  int i = blockIdx.x;
  int bh = 2 * (i & 7) + ((i >> 3) & 1);
  int q0 = (i >> 4) * 64;
  int kstart = q0 & ~255;  // frame-aligned reverse-causal mask
  const unsigned short* qbase = qb + (size_t)bh * SEQ * HDP;
  const unsigned short* kbase = kb + (size_t)bh * SEQ * HDP;
  const unsigned short* vbase = vt + (size_t)bh * HDP * SEQ;
  int myrow = q0 + wv * 16;
  bf16x8 a0 = ldb8(qbase + (size_t)(myrow + c) * HDP + q * 8);
  bf16x8 a1 = ldb8(qbase + (size_t)(myrow + c) * HDP + 32 + q * 8);
  floatx4 O[3] = {};
  float mr[4] = {-3e38f, -3e38f, -3e38f, -3e38f};
  float lr[4] = {0.f, 0.f, 0.f, 0.f};
  int srow = tid >> 2, schunk = (tid & 3) * 16;
  for (int k0 = kstart; k0 < SEQ; k0 += 64) {
    const unsigned short* kg = kbase + (size_t)(k0 + srow) * HDP + schunk;
    *(ushort8*)(&Ks[srow][schunk]) = *(const ushort8*)kg;
    *(ushort8*)(&Ks[srow][schunk + 8]) = *(const ushort8*)(kg + 8);
    if (srow < 48) {
      const unsigned short* vg = vbase + (size_t)srow * SEQ + k0 + schunk;
      *(ushort8*)(&Vs[srow][schunk]) = *(const ushort8*)vg;
      *(ushort8*)(&Vs[srow][schunk + 8]) = *(const ushort8*)(vg + 8);
    }
    __syncthreads();
    floatx4 S[4];
#pragma unroll
    for (int t = 0; t < 4; t++) {
      bf16x8 b0 = ldb8(&Ks[t * 16 + c][q * 8]);
      bf16x8 b1 = ldb8(&Ks[t * 16 + c][32 + q * 8]);
      floatx4 z = {};
      z = MFMA(a0, b0, z);
      S[t] = MFMA(a1, b1, z);
    }
    float alpha[4];
#pragma unroll
    for (int r = 0; r < 4; r++) {
      float m0 = fmaxf(fmaxf(S[0][r], S[1][r]), fmaxf(S[2][r], S[3][r]));
#pragma unroll
      for (int msk = 1; msk < 16; msk <<= 1) m0 = fmaxf(m0, __shfl_xor(m0, msk, 16));
      float nm = fmaxf(mr[r], m0);
      alpha[r] = __expf(mr[r] - nm);
      mr[r] = nm;
      lr[r] *= alpha[r];
    }
#pragma unroll
    for (int t = 0; t < 4; t++)
#pragma unroll
      for (int r = 0; r < 4; r++) {
        float pv = __expf(S[t][r] - mr[r]);
        lr[r] += pv;
        Pt[wv][q * 4 + r][t * 16 + c] = f2bf(pv);
      }
#pragma unroll
    for (int f = 0; f < 3; f++)
#pragma unroll
      for (int r = 0; r < 4; r++) O[f][r] *= alpha[r];
    bf16x8 pa0 = ldb8(&Pt[wv][c][q * 8]);
    bf16x8 pa1 = ldb8(&Pt[wv][c][32 + q * 8]);
#pragma unroll
    for (int f = 0; f < 3; f++) {
      bf16x8 v0 = ldb8(&Vs[f * 16 + c][q * 8]);
      bf16x8 v1 = ldb8(&Vs[f * 16 + c][32 + q * 8]);
      O[f] = MFMA(pa0, v0, O[f]);
      O[f] = MFMA(pa1, v1, O[f]);
    }
    __syncthreads();
  }
#pragma unroll
  for (int r = 0; r < 4; r++) {
#pragma unroll
    for (int msk = 1; msk < 16; msk <<= 1) lr[r] += __shfl_xor(lr[r], msk, 16);
    lr[r] = 1.0f / lr[r];
  }
  int b = bh >> 3, h = bh & 7;
#pragma unroll
  for (int f = 0; f < 3; f++)
#pragma unroll
    for (int r = 0; r < 4; r++)
      obuf[((size_t)b * SEQ + myrow + q * 4 + r) * DIM + h * HD + f * 16 + c] =
          f2bf(O[f][r] * lr[r]);
}

// ---------------- stable argsort(-mask) ranks via block scan ----------------
__global__ __launch_bounds__(256) void rank_kernel(const int* __restrict__ mask,
                                                   int* __restrict__ dest) {
  __shared__ int wsum[4];
  int b = blockIdx.x, t = threadIdx.x;
  int lane = t & 63, wv = t >> 6;
  const int* mb = mask + b * SEQ;
  int base = t * 8;
  int v[8];
  int s = 0;
#pragma unroll
  for (int j = 0; j < 8; j++) { v[j] = mb[base + j]; s += v[j]; }
  int incl = s;
  for (int off = 1; off < 64; off <<= 1) {
    int n = __shfl_up(incl, off);
    if (lane >= off) incl += n;
  }
  if (lane == 63) wsum[wv] = incl;
  __syncthreads();
  int P = incl - s;
  for (int w = 0; w < wv; w++) P += wsum[w];
  int run = 0;
#pragma unroll
  for (int j = 0; j < 8; j++) {
    int ones = P + run;
    int l = base + j;
    dest[b * SEQ + l] = v[j] ? ones : 512 + (l - ones);
    run += v[j];
  }
}

// ---------------- write decoded_full + scattered visible/masked ----------------
__global__ __launch_bounds__(256) void output_kernel(const float* __restrict__ x,
                                                     const int* __restrict__ dest,
                                                     float* __restrict__ out) {
  int idx = blockIdx.x * 256 + threadIdx.x;  // NB*SEQ*96
  int row = idx / 96, c = idx % 96;
  float4 v = ((const float4*)(x + (size_t)row * DIM))[c];
  ((float4*)(out + (size_t)row * DIM))[c] = v;
  int b = row >> 11;
  int d = dest[row];
  size_t base = (size_t)NB * SEQ * DIM;
  size_t o;
  if (d < 512) o = base + ((size_t)b * 512 + d) * DIM;
  else o = base + (size_t)NB * 512 * DIM + ((size_t)b * 1536 + (d - 512)) * DIM;
  ((float4*)(out + o))[c] = v;
}

extern "C" void kernel_launch(void* const* d_in, const int* in_sizes, int n_in,
                              void* d_out, int out_size, void* d_ws, size_t ws_size,
                              hipStream_t stream) {
  const float* vis = (const float*)d_in[0];
  const int* ids = (const int*)d_in[1];
  const int* mask = (const int*)d_in[2];
  const float* mask_token = (const float*)d_in[6];
  const float* ln_in_w = (const float*)d_in[7];
  const float* ln1_w = (const float*)d_in[8];
  const float* ln2_w = (const float*)d_in[9];
  const float* Wq = (const float*)d_in[10];
  const float* bq = (const float*)d_in[11];
  const float* Wk = (const float*)d_in[12];
  const float* bk = (const float*)d_in[13];
  const float* Wv = (const float*)d_in[14];
  const float* bv = (const float*)d_in[15];
  const float* Wo = (const float*)d_in[16];
  const float* bo = (const float*)d_in[17];
  const float* W1 = (const float*)d_in[18];
  const float* b1 = (const float*)d_in[19];
  const float* W2 = (const float*)d_in[20];
  const float* b2 = (const float*)d_in[21];

  char* p = (char*)d_ws;
  size_t off = 0;
  auto alloc = [&](size_t n) -> void* {
    off = (off + 255) & ~(size_t)255;
    void* r = p + off;
    off += n;
    return r;
  };
  unsigned short* wqkvT = (unsigned short*)alloc((size_t)NLAYER * 1152 * DIM * 2);
  unsigned short* woT = (unsigned short*)alloc((size_t)NLAYER * DIM * DIM * 2);
  unsigned short* w1T = (unsigned short*)alloc((size_t)NLAYER * DIM * FF * 2);
  unsigned short* w2T = (unsigned short*)alloc((size_t)NLAYER * DIM * FF * 2);
  float* bqkv = (float*)alloc((size_t)NLAYER * 1152 * 4);
  float* cosT = (float*)alloc((size_t)SEQ * HD * 4);
  float* sinT = (float*)alloc((size_t)SEQ * HD * 4);
  float* x = (float*)alloc((size_t)NB * SEQ * DIM * 4);
  unsigned short* hdn = (unsigned short*)alloc((size_t)NB * SEQ * DIM * 2);
  unsigned short* qpre = (unsigned short*)alloc((size_t)NB * SEQ * DIM * 2);
  unsigned short* kpre = (unsigned short*)alloc((size_t)NB * SEQ * DIM * 2);
  unsigned short* qb = (unsigned short*)alloc((size_t)NB * NH * SEQ * HDP * 2);
  unsigned short* kb = (unsigned short*)alloc((size_t)NB * NH * SEQ * HDP * 2);
  unsigned short* vtb = (unsigned short*)alloc((size_t)NB * NH * SEQ * HDP * 2);
  unsigned short* obuf = (unsigned short*)alloc((size_t)NB * SEQ * DIM * 2);
  unsigned short* a1 = (unsigned short*)alloc((size_t)NB * SEQ * FF * 2);
  int* dest = (int*)alloc((size_t)NB * SEQ * 4);

  // zero head-dim pad [48,64): q/k pads are contracted over by score MFMAs.
  hipMemsetAsync(qb, 0, (size_t)NB * NH * SEQ * HDP * 2, stream);
  hipMemsetAsync(kb, 0, (size_t)NB * NH * SEQ * HDP * 2, stream);

  dim3 tb(32, 8);
  wtrans_kernel<<<dim3(12, 12, 8), tb, 0, stream>>>(Wq, wqkvT, 384, 384, 147456, 442368);
  wtrans_kernel<<<dim3(12, 12, 8), tb, 0, stream>>>(Wk, wqkvT + 147456, 384, 384, 147456, 442368);
  wtrans_kernel<<<dim3(12, 12, 8), tb, 0, stream>>>(Wv, wqkvT + 294912, 384, 384, 147456, 442368);
  wtrans_kernel<<<dim3(12, 12, 8), tb, 0, stream>>>(Wo, woT, 384, 384, 147456, 147456);
  wtrans_kernel<<<dim3(48, 12, 8), tb, 0, stream>>>(W1, w1T, 384, 1536, 589824, 589824);
  wtrans_kernel<<<dim3(12, 48, 8), tb, 0, stream>>>(W2, w2T, 1536, 384, 589824, 589824);
  biascat_kernel<<<(NLAYER * 1152 + 255) / 256, 256, 0, stream>>>(bq, bk, bv, bqkv);
  ropetab_kernel<<<(SEQ * HD + 255) / 256, 256, 0, stream>>>(cosT, sinT);
  gatherrms_kernel<<<NB * SEQ / 4, 256, 0, stream>>>(vis, ids, mask_token, ln_in_w, x);

  for (int i = 0; i < NLAYER; i++) {
    size_t wo = (size_t)i * DIM * DIM;
    size_t wf = (size_t)i * DIM * FF;
    rmsbf_kernel<<<NB * SEQ / 4, 256, 0, stream>>>(x, ln1_w + i * DIM, hdn);
    gemm128_kernel<<<dim3(32, 9), 256, 0, stream>>>(hdn, wqkvT + (size_t)i * 442368, bqkv + i * 1152,
                                                    NB * SEQ, 1152, DIM, 4, qpre, kpre, vtb, nullptr);
    rope_kernel<<<NB * SEQ, 384, 0, stream>>>(qpre, kpre, cosT, sinT, qb, kb);
    fattn_kernel<<<512, 256, 0, stream>>>(qb, kb, vtb, obuf);
    gemm_kernel<<<dim3(64, 6), 256, 0, stream>>>(obuf, woT + wo, bo + i * DIM, NB * SEQ, DIM, DIM, 2,
                                                 nullptr, nullptr, nullptr, x);
    rmsbf_kernel<<<NB * SEQ / 4, 256, 0, stream>>>(x, ln2_w + i * DIM, hdn);
    gemm128_kernel<<<dim3(32, 12), 256, 0, stream>>>(hdn, w1T + wf, b1 + i * FF, NB * SEQ, FF, DIM, 3,
                                                     a1, nullptr, nullptr, nullptr);
    gemm_kernel<<<dim3(64, 6), 256, 0, stream>>>(a1, w2T + wf, b2 + i * DIM, NB * SEQ, DIM, FF, 2,
                                                 nullptr, nullptr, nullptr, x);
  }
  rank_kernel<<<NB, 256, 0, stream>>>(mask, dest);
  output_kernel<<<NB * SEQ * 96 / 256, 256, 0, stream>>>(x, dest, (float*)d_out);
}